// Round 1
// baseline (108.049 us; speedup 1.0000x reference)
//
#include <hip/hip_runtime.h>

// DenseIouPred: reference reads only slice 0 of each batched input.
//   output: (64,16,4,72,72) f32 -> out0 = first 4*72*72 floats, layout [d][r][c]
//   ind:    (64,16,1) i32      -> ind0 = ind[0]; ch = ind0/72, cw = ind0%72
//   target: (64,16,4) f32      -> tgt0 = target[0..3]
//   radius: scalar int (10)
// Result: (72,72) f32 map, zero outside the (2R+1)^2 window around (ch,cw);
// inside window, IoU where t-box conditions hold, else 0. Scatter indices are
// unique and invalid points are dropped (== left at zero), so a direct
// per-output-cell gather reproduces the scatter exactly.

__global__ void dense_iou_pred_kernel(const float* __restrict__ output,
                                      const int* __restrict__ ind,
                                      const float* __restrict__ target,
                                      const int* __restrict__ radius_p,
                                      float* __restrict__ out) {
    constexpr int W = 72, H = 72, WH = W * H;
    int idx = blockIdx.x * blockDim.x + threadIdx.x;
    if (idx >= WH) return;

    int r = idx / H;   // hh
    int c = idx % H;   // ww

    int radius = radius_p[0];
    int ind0 = ind[0];
    int cw = ind0 % W;
    int ch = ind0 / W;

    int r_h = r - ch;
    int r_w = c - cw;

    float val = 0.0f;
    if (r_h >= -radius && r_h <= radius && r_w >= -radius && r_w <= radius) {
        float fw = (float)r_w;
        float fh = (float)r_h;
        float t_wl = target[0] + fw;
        float t_wr = target[1] - fw;
        float t_ht = target[2] + fh;
        float t_hb = target[3] - fh;
        if (t_wl >= 0.0f && t_wr >= 0.0f && t_ht >= 0.0f && t_hb >= 0.0f) {
            // hh/ww in-range checks are implied by (r,c) in [0,72)^2
            float p_l = output[0 * WH + idx];
            float p_r = output[1 * WH + idx];
            float p_t = output[2 * WH + idx];
            float p_b = output[3 * WH + idx];
            float t_area = (t_wl + t_wr) * (t_ht + t_hb);
            float p_area = (p_l + p_r) * (p_t + p_b);
            float w_int = fminf(p_l, t_wl) + fminf(p_r, t_wr);
            float h_int = fminf(p_b, t_hb) + fminf(p_t, t_ht);
            float inter = w_int * h_int;
            float uni = t_area + p_area - inter;
            val = (inter + 1.0f) / (uni + 1.0f);
        }
    }
    out[idx] = val;
}

extern "C" void kernel_launch(void* const* d_in, const int* in_sizes, int n_in,
                              void* d_out, int out_size, void* d_ws, size_t ws_size,
                              hipStream_t stream) {
    const float* output = (const float*)d_in[0];
    const int*   ind    = (const int*)d_in[1];
    const float* target = (const float*)d_in[2];
    const int*   radius = (const int*)d_in[3];
    float* out = (float*)d_out;

    constexpr int WH = 72 * 72;
    constexpr int BLOCK = 256;
    dim3 grid((WH + BLOCK - 1) / BLOCK);
    dense_iou_pred_kernel<<<grid, BLOCK, 0, stream>>>(output, ind, target, radius, out);
}